// Round 6
// baseline (1092.903 us; speedup 1.0000x reference)
//
#include <hip/hip_runtime.h>
#include <stdint.h>

static constexpr int B  = 32;
static constexpr int T  = 350;
static constexpr int NIN = 2048;
static constexpr int NH  = 512;
static constexpr int NO  = 10;
static constexpr int BT  = B * T;

static constexpr int GRID = 512;                       // 2 blocks/CU x 256 CU

static constexpr float THETA = 10.0f;
static constexpr float BETA  = 0.36787944117144233f;   // e^-1 (refractory decay)
static constexpr float CREF  = 54.365636569180904707f; // SCALE_REF*THETA*e = 20e

// Workspace layout (bytes) — identical to R4, plus barrier counters at the end.
static constexpr size_t OFF_W1TS = 0;                   // 4,196,352
static constexpr size_t OFF_MASK = 4196352;             // 32*32*352 u64 = 2,883,584
static constexpr size_t OFF_SRM  = 7080960;             // 192 f32 (1 KB slot)
static constexpr size_t OFF_Z1   = 7081984;             // BT*512 f32 = 22,937,600
static constexpr size_t OFF_A1   = 30019584;            // BT*512 f32
static constexpr size_t OFF_LST  = OFF_A1;              // BT*192 u16 (dead before fir writes a1)
static constexpr size_t OFF_CNT  = OFF_A1 + 4300800;    // BT*4
static constexpr size_t OFF_SMK  = 52957184;            // BT*8 u64 = 716,800
static constexpr size_t OFF_BAR  = 53673984;            // 5 ints (zeroed per iteration)

static constexpr int SLICE_F = 8;
static constexpr int NSLICE  = NH / SLICE_F;             // 64
static constexpr int SLICE_STRIDE = 2049 * SLICE_F;      // 16392 floats

// Software grid barrier. Safe because all GRID blocks are co-resident by
// construction (65,568 B LDS + __launch_bounds__(256,2) => exactly 2/CU).
// Release: __syncthreads (drains vmcnt) + __threadfence (agent-scope, makes
// stores device-visible incl. cross-XCD). Acquire: agent-scope atomic load
// + trailing __threadfence (invalidates L1, as a kernel boundary would).
__device__ __forceinline__ void gbar(int* cnt, int idx) {
    __syncthreads();
    __threadfence();
    if (threadIdx.x == 0) {
        atomicAdd(cnt + idx, 1);
        while (__hip_atomic_load(cnt + idx, __ATOMIC_ACQUIRE,
                                 __HIP_MEMORY_SCOPE_AGENT) < GRID) {
            __builtin_amdgcn_s_sleep(1);
        }
    }
    __syncthreads();
    __threadfence();
}

// ============ k_all (R6): single persistent kernel, 512 blocks x 256 thr,
// 65,568 B static LDS -> exactly 2 blocks/CU. Phase bodies verbatim R4
// (bit-exact); 5 software grid barriers replace 5 launch boundaries.
__global__ void __launch_bounds__(256, 2) k_all(const float* __restrict__ x,
                                                const float* __restrict__ W1,
                                                const float* __restrict__ W2,
                                                float* __restrict__ W1Ts,
                                                uint64_t* __restrict__ mask,
                                                float* __restrict__ srm28,
                                                uint16_t* glst,          // aliases a1 (time-disjoint)
                                                int* __restrict__ gcnt,
                                                float* __restrict__ z1,
                                                float* a1,               // aliases glst
                                                uint64_t* __restrict__ smaskg,
                                                int* __restrict__ bar,
                                                float* __restrict__ out) {
    __shared__ __align__(16) char smem[65568];
    int bid = blockIdx.x;
    int tid = threadIdx.x;

    // ================= P1: prep (pack + W1 transpose + srm/zero) =================
    for (int vb = bid; vb < 2049; vb += GRID) {
        if (vb < 1024) {
            uint64_t (*tb)[64] = (uint64_t(*)[64])smem;     // 3 KB
            int b = vb >> 5, nblk = vb & 31;
            int wv = tid >> 6, lane = tid & 63;
            for (int g = 0; g < 4; ++g) {
                float v[4][6];
                #pragma unroll
                for (int i = 0; i < 4; ++i) {
                    int nr = wv + 4 * (4 * g + i);
                    const float* xp = x + ((size_t)b * NIN + nblk * 64 + nr) * T;
                    #pragma unroll
                    for (int c = 0; c < 6; ++c) {
                        int t = c * 64 + lane;
                        v[i][c] = (t < T) ? xp[t] : 0.f;
                    }
                }
                #pragma unroll
                for (int i = 0; i < 4; ++i) {
                    int nr = wv + 4 * (4 * g + i);
                    #pragma unroll
                    for (int c = 0; c < 6; ++c) {
                        uint64_t mk = __ballot(v[i][c] != 0.0f);
                        if (lane == 0) tb[c][nr] = mk;
                    }
                }
            }
            __syncthreads();
            static const uint64_t AM[6] = {
                0x00000000FFFFFFFFull, 0x0000FFFF0000FFFFull, 0x00FF00FF00FF00FFull,
                0x0F0F0F0F0F0F0F0Full, 0x3333333333333333ull, 0x5555555555555555ull };
            for (int c = wv; c < 6; c += 4) {
                uint64_t w = tb[c][lane];            // lane = n, bits = t
                #pragma unroll
                for (int i = 0; i < 6; ++i) {
                    int s = 32 >> i;
                    uint64_t A = AM[i];
                    uint64_t y = __shfl_xor((unsigned long long)w, s);
                    if ((lane & s) == 0) w = (w & A)  | ((y & A) << s);
                    else                 w = (w & ~A) | ((y & ~A) >> s);
                }
                int t = c * 64 + lane;               // lane = t, bits = n
                if (t < T) mask[((size_t)b * 32 + nblk) * 352 + t] = w;
            }
        } else if (vb < 2048) {
            float (*tile)[33] = (float(*)[33])smem;          // 4.2 KB
            int idx = vb - 1024;
            int n0 = (idx & 63) * 32, m0 = (idx >> 6) * 32;
            int tx = tid & 31, ty0 = tid >> 5;
            #pragma unroll
            for (int i = 0; i < 4; ++i) {
                int ty = ty0 + 8 * i;
                tile[ty][tx] = W1[(size_t)(m0 + ty) * NIN + n0 + tx];
            }
            __syncthreads();
            #pragma unroll
            for (int i = 0; i < 4; ++i) {
                int ty = ty0 + 8 * i;
                int n = n0 + ty, m = m0 + tx;
                W1Ts[(size_t)(m >> 3) * SLICE_STRIDE + n * SLICE_F + (m & 7)] = tile[tx][ty];
            }
        } else {
            int j = tid;
            if (j < 192) {
                float v = 0.f;
                int i = j - 28;
                if (i >= 0 && i < 100) { float t = (float)i; v = (t * 0.1f) * expf(1.f - t * 0.1f); }
                srm28[j] = v;
            }
            for (int i = j; i < NSLICE * SLICE_F; i += 256)
                W1Ts[(size_t)(i >> 3) * SLICE_STRIDE + 2048 * SLICE_F + (i & 7)] = 0.f;
        }
        __syncthreads();   // protect smem reuse across vb iterations (block-uniform)
    }
    gbar(bar, 0);

    // ================= P2: decode (per-wave; uniform 6-iter loop) =================
    {
        int w = tid >> 6, lane = tid & 63;
        uint16_t* lst = (uint16_t*)smem + w * 200;   // 400 B per wave
        int vw = bid * 4 + w;                        // 0..2047
        for (int k = 0; k < 6; ++k) {
            int row = vw + 2048 * k;
            bool act = (row < BT);
            int padded = 0;
            if (act) {
                int b = row / T, t = row - b * T;
                uint64_t wd = (lane < 32) ? mask[((size_t)b * 32 + lane) * 352 + t] : 0ull;
                int cnt = __popcll(wd);
                int pre = cnt;
                #pragma unroll
                for (int off = 1; off < 64; off <<= 1) {
                    int v = __shfl_up(pre, off);
                    if (lane >= off) pre += v;
                }
                int total = __shfl(pre, 63);
                int excl = pre - cnt;
                while (wd) {
                    int bit = __builtin_ctzll(wd);
                    wd &= wd - 1;
                    lst[excl++] = (uint16_t)((lane << 6) + bit);
                }
                padded = (total + 7) & ~7;
                if (lane < padded - total) lst[total + lane] = 2048;   // zero-row pad
            }
            __syncthreads();    // uniform across all 4 waves
            if (act) {
                uint16_t* op = glst + (size_t)row * 192;
                for (int i = lane; i < padded; i += 64) op[i] = lst[i];
                if (lane == 0) gcnt[row] = padded;
            }
            __syncthreads();
        }
    }
    gbar(bar, 1);

    // ================= P3: z1 gather (verbatim k_z1s; 512 blocks exact) ==========
    {
        float* w1s = (float*)smem;                  // 65,568 B
        int s = bid & 63;
        int bt0 = (bid >> 6) * (BT / 8);            // 1400 rows per block
        const float4* src = (const float4*)(W1Ts + (size_t)s * SLICE_STRIDE);
        for (int i = tid; i < SLICE_STRIDE / 4; i += 256)
            ((float4*)w1s)[i] = src[i];
        __syncthreads();

        int q  = tid & 1;
        int rl = tid >> 1;
        for (int rr = rl; rr < BT / 8; rr += 128) {
            int row = bt0 + rr;
            int padded = gcnt[row];
            const ushort4* lp = (const ushort4*)(glst + (size_t)row * 192);
            float4 acc = {0, 0, 0, 0};
            for (int k = 0; k < padded; k += 8) {
                ushort4 q0 = lp[k >> 2];
                ushort4 q1 = lp[(k >> 2) + 1];
                const float* base = w1s + q * 4;
                float4 x0 = *(const float4*)(base + q0.x * SLICE_F);
                float4 x1 = *(const float4*)(base + q0.y * SLICE_F);
                float4 x2 = *(const float4*)(base + q0.z * SLICE_F);
                float4 x3 = *(const float4*)(base + q0.w * SLICE_F);
                float4 x4 = *(const float4*)(base + q1.x * SLICE_F);
                float4 x5 = *(const float4*)(base + q1.y * SLICE_F);
                float4 x6 = *(const float4*)(base + q1.z * SLICE_F);
                float4 x7 = *(const float4*)(base + q1.w * SLICE_F);
                acc.x += x0.x; acc.y += x0.y; acc.z += x0.z; acc.w += x0.w;
                acc.x += x1.x; acc.y += x1.y; acc.z += x1.z; acc.w += x1.w;
                acc.x += x2.x; acc.y += x2.y; acc.z += x2.z; acc.w += x2.w;
                acc.x += x3.x; acc.y += x3.y; acc.z += x3.z; acc.w += x3.w;
                acc.x += x4.x; acc.y += x4.y; acc.z += x4.z; acc.w += x4.w;
                acc.x += x5.x; acc.y += x5.y; acc.z += x5.z; acc.w += x5.w;
                acc.x += x6.x; acc.y += x6.y; acc.z += x6.z; acc.w += x6.w;
                acc.x += x7.x; acc.y += x7.y; acc.z += x7.z; acc.w += x7.w;
            }
            *(float4*)(z1 + (size_t)row * NH + s * SLICE_F + q * 4) = acc;
        }
    }
    gbar(bar, 2);

    // ================= P4: fir1 (verbatim R4 Toeplitz; one wave per vblock) ======
    {
        float* tbf = (float*)smem;                  // 192 floats
        for (int i = tid; i < 192; i += 256) tbf[i] = srm28[i];
        __syncthreads();
        int w = tid >> 6, lane = tid & 63;
        int vw = bid * 4 + w;                        // 0..2047; 1408 active
        if (vw < 1408) {
            int b = vw & 31, half = (vw >> 5) & 1, tg = vw >> 6;  // tg 0..21
            int t0 = tg * 16;
            int m = half * 256 + lane * 4;
            const float* sp = z1 + (size_t)b * T * NH + m;

            float4 acc[16];
            #pragma unroll
            for (int r = 0; r < 16; ++r) acc[r] = make_float4(0.f, 0.f, 0.f, 0.f);

            int o_start = (99 - t0) >> 4;
            if (o_start < 0) o_start = 0;

            for (int o = o_start; o < 7; ++o) {      // NOT unrolled (R3 lesson)
                float cw[31];
                int cb = 112 - 16 * o;
                #pragma unroll
                for (int kk = 0; kk < 31; ++kk) cw[kk] = tbf[cb + kk];
                int dd0 = o * 16;
                #pragma unroll
                for (int j = 0; j < 16; ++j) {
                    int tau = t0 - 99 + dd0 + j;
                    float4 v = make_float4(0.f, 0.f, 0.f, 0.f);
                    if (tau >= 0 && tau < T) v = *(const float4*)(sp + (size_t)tau * NH);
                    #pragma unroll
                    for (int r = 0; r < 16; ++r) {
                        float c = cw[r - j + 15];
                        acc[r].x += c * v.x; acc[r].y += c * v.y;
                        acc[r].z += c * v.z; acc[r].w += c * v.w;
                    }
                }
            }
            {   // o == 7 tail
                float e1 = tbf[29], e2 = tbf[30];
                int tau = t0 + 13;
                if (tau < T) {
                    float4 v = *(const float4*)(sp + (size_t)tau * NH);
                    acc[14].x += e1 * v.x; acc[14].y += e1 * v.y;
                    acc[14].z += e1 * v.z; acc[14].w += e1 * v.w;
                    acc[15].x += e2 * v.x; acc[15].y += e2 * v.y;
                    acc[15].z += e2 * v.z; acc[15].w += e2 * v.w;
                }
                tau = t0 + 14;
                if (tau < T) {
                    float4 v = *(const float4*)(sp + (size_t)tau * NH);
                    acc[15].x += e1 * v.x; acc[15].y += e1 * v.y;
                    acc[15].z += e1 * v.z; acc[15].w += e1 * v.w;
                }
            }
            #pragma unroll
            for (int r = 0; r < 16; ++r) {
                int t = t0 + r;
                if (t < T) *(float4*)(a1 + ((size_t)b * T + t) * NH + m) = acc[r];
            }
        }
    }
    gbar(bar, 3);

    // ================= P5: scan1 (verbatim; wave 0 of even blocks = 256 waves) ===
    {
        if ((bid & 1) == 0 && tid < 64) {
            constexpr int CT = 16;
            constexpr int NC = (T + CT - 1) / CT;   // 22
            int tg = (bid >> 1) * 64 + tid;
            int b = tg >> 9, m = tg & 511;
            int w8 = m >> 6;
            const float* up = a1 + (size_t)b * T * NH + m;
            float A = 0.f, Bs = 0.f;
            float c0[CT], c1[CT], c2[CT];
            #pragma unroll
            for (int j = 0; j < CT; ++j) c0[j] = up[(size_t)j * NH];
            #pragma unroll
            for (int j = 0; j < CT; ++j) {
                int t = CT + j;
                c1[j] = (t < T) ? up[(size_t)t * NH] : 0.f;
            }
            for (int c = 0; c < NC; ++c) {
                int t0 = c * CT;
                int nsteps = (T - t0 < CT) ? (T - t0) : CT;
                if (c + 2 < NC) {
                    #pragma unroll
                    for (int j = 0; j < CT; ++j) {
                        int t = t0 + 2 * CT + j;
                        c2[j] = (t < T) ? up[(size_t)t * NH] : 0.f;
                    }
                }
                #pragma unroll
                for (int j = 0; j < CT; ++j) {
                    if (j < nsteps) {                 // uniform -> safe ballot
                        float mem = c0[j] - CREF * Bs;
                        float sp = (mem >= THETA) ? 1.0f : 0.0f;
                        A = sp + BETA * A;
                        Bs = BETA * (Bs + A);
                        uint64_t mk = __ballot(sp != 0.0f);
                        if (tid == 0) smaskg[((size_t)b * T + t0 + j) * 8 + w8] = mk;
                    }
                }
                #pragma unroll
                for (int j = 0; j < CT; ++j) { c0[j] = c1[j]; c1[j] = c2[j]; }
            }
        }
    }
    gbar(bar, 4);

    // ================= P6: tail (verbatim; 32 spread blocks) =====================
    if ((bid & 15) == 0) {
        int b = bid >> 4;                           // 0..31
        float*    w2s_ab = (float*)smem;                      // 20,480 B
        uint64_t* smk    = (uint64_t*)(smem + 20480);         // 22,400 B
        float*    tbf    = (float*)(smem + 42880);            //    768 B
        float*    zb     = (float*)(smem + 43648);            // 15,464 B (stride 11)
        for (int i = tid; i < NO * NH; i += 256) w2s_ab[i] = W2[i];
        const uint64_t* mp = smaskg + (size_t)b * T * 8;
        for (int i = tid; i < T * 8; i += 256) smk[i] = mp[i];
        if (tid < 192) tbf[tid] = srm28[tid];
        __syncthreads();
        // ---- z2 gather: ascending w8 / ascending bit = ascending m (bit-exact)
        for (int i = tid; i < T * NO; i += 256) {
            int t = i / NO, o = i - t * NO;
            const float* wrow = w2s_ab + o * NH;
            float acc = 0.f;
            #pragma unroll
            for (int w8 = 0; w8 < 8; ++w8) {
                uint64_t mk = smk[t * 8 + w8];
                int base = w8 * 64;
                while (mk) {
                    int bit = __builtin_ctzll(mk);
                    mk &= mk - 1;
                    acc += wrow[base + bit];
                }
            }
            zb[t * 11 + o] = acc;
        }
        __syncthreads();
        // ---- fir2: zb -> ab (ab aliases w2s, dead after gather)
        float* ab = w2s_ab;
        if (tid < 220) {
            int tt = tid / 10, o = tid - tt * 10;
            int t0 = tt * 16;
            float acc[16];
            #pragma unroll
            for (int r = 0; r < 16; ++r) acc[r] = 0.f;
            float c[16];
            #pragma unroll
            for (int r = 0; r < 16; ++r) c[r] = tbf[r + 127];
            for (int oo = 0; oo < 8; ++oo) {
                #pragma unroll
                for (int j = 0; j < 16; ++j) {
                    int dd = oo * 16 + j;
                    int tau = t0 - 99 + dd;
                    float v = (tau >= 0 && tau < T) ? zb[tau * 11 + o] : 0.f;
                    #pragma unroll
                    for (int r = 0; r < 16; ++r) acc[r] += c[r] * v;
                    #pragma unroll
                    for (int r = 15; r > 0; --r) c[r] = c[r - 1];
                    int ci = 126 - dd;
                    c[0] = tbf[ci < 0 ? 0 : ci];
                }
            }
            #pragma unroll
            for (int r = 0; r < 16; ++r) {
                int t = t0 + r;
                if (t < T) ab[t * 10 + o] = acc[r];
            }
        }
        __syncthreads();
        // ---- final refractory scan -> out [B][NO][T]
        if (tid < NO) {
            int o = tid;
            float A2 = 0.f, B2 = 0.f;
            float* op = out + ((size_t)b * NO + o) * T;
            for (int t = 0; t < T; ++t) {
                float mem = ab[t * 10 + o] - CREF * B2;
                float sp = (mem >= THETA) ? 1.0f : 0.0f;
                A2 = sp + BETA * A2;
                B2 = BETA * (B2 + A2);
                op[t] = sp;
            }
        }
    }
}

extern "C" void kernel_launch(void* const* d_in, const int* in_sizes, int n_in,
                              void* d_out, int out_size, void* d_ws, size_t ws_size,
                              hipStream_t stream) {
    const float* x  = (const float*)d_in[0];
    const float* W1 = (const float*)d_in[1];
    const float* W2 = (const float*)d_in[2];
    char* ws = (char*)d_ws;
    float*    W1Ts   = (float*)(ws + OFF_W1TS);
    uint64_t* mask   = (uint64_t*)(ws + OFF_MASK);
    float*    srm    = (float*)(ws + OFF_SRM);
    float*    z1     = (float*)(ws + OFF_Z1);
    float*    a1     = (float*)(ws + OFF_A1);
    uint16_t* glst   = (uint16_t*)(ws + OFF_LST);   // overlays a1 (time-disjoint)
    int*      gcnt   = (int*)(ws + OFF_CNT);
    uint64_t* smaskg = (uint64_t*)(ws + OFF_SMK);
    int*      bar    = (int*)(ws + OFF_BAR);
    float*    out    = (float*)d_out;

    // zero the 5 barrier counters (workspace is poisoned每 iteration);
    // memset node is graph-capture legal.
    hipMemsetAsync(bar, 0, 64, stream);
    hipLaunchKernelGGL(k_all, dim3(GRID), dim3(256), 0, stream,
                       x, W1, W2, W1Ts, mask, srm, glst, gcnt, z1, a1,
                       smaskg, bar, out);
}

// Round 15
// 687.922 us; speedup vs baseline: 1.5887x; 1.5887x over previous
//
#include <hip/hip_runtime.h>
#include <stdint.h>

static constexpr int B  = 32;
static constexpr int T  = 350;
static constexpr int NIN = 2048;
static constexpr int NH  = 512;
static constexpr int NO  = 10;
static constexpr int BT  = B * T;

static constexpr int GRID = 512;                       // 2 blocks/CU x 256 CU

static constexpr float THETA = 10.0f;
static constexpr float BETA  = 0.36787944117144233f;   // e^-1 (refractory decay)
static constexpr float CREF  = 54.365636569180904707f; // SCALE_REF*THETA*e = 20e

// Workspace layout (bytes) — identical to R4, plus barrier counters at the end.
static constexpr size_t OFF_W1TS = 0;                   // 4,196,352
static constexpr size_t OFF_MASK = 4196352;             // 32*32*352 u64 = 2,883,584
static constexpr size_t OFF_SRM  = 7080960;             // 192 f32 (1 KB slot)
static constexpr size_t OFF_Z1   = 7081984;             // BT*512 f32 = 22,937,600
static constexpr size_t OFF_A1   = 30019584;            // BT*512 f32
static constexpr size_t OFF_LST  = OFF_A1;              // BT*192 u16 (dead before fir writes a1)
static constexpr size_t OFF_CNT  = OFF_A1 + 4300800;    // BT*4
static constexpr size_t OFF_SMK  = 52957184;            // BT*8 u64 = 716,800
static constexpr size_t OFF_BAR  = 53673984;            // 5 ints (zeroed per iteration)

static constexpr int SLICE_F = 8;
static constexpr int NSLICE  = NH / SLICE_F;             // 64
static constexpr int SLICE_STRIDE = 2049 * SLICE_F;      // 16392 floats

// Software grid barrier — R14. R6's per-poll ACQUIRE loads caused a
// continuous all-XCD L2 invalidation storm (1067 us, VALUBusy 0.2%).
// This version: one __threadfence (seq_cst agent fence — release side)
// before the arrive-add, RELAXED polls (no cache ops; agent-scope load
// reads at the device coherence point so remote adds are visible) with
// s_sleep backoff, one __threadfence after the count is observed
// (acquire side). Only symbols that compiled+ran in R6 are used
// (__hip_atomic_fence does NOT exist on this ROCm — R13 compile error).
// Liveness: all GRID blocks co-resident by construction (65,568 B LDS +
// launch_bounds(256,2)); R6 ran this exact geometry to completion.
__device__ __forceinline__ void gbar(int* cnt, int idx) {
    __syncthreads();
    if (threadIdx.x == 0) {
        __threadfence();                               // release: drain stores to device scope
        atomicAdd(cnt + idx, 1);                       // device-scope by default (m20)
        while (__hip_atomic_load(cnt + idx, __ATOMIC_RELAXED,
                                 __HIP_MEMORY_SCOPE_AGENT) < GRID) {
            __builtin_amdgcn_s_sleep(8);               // ~512 cyc between polls
        }
        __threadfence();                               // acquire: invalidate stale lines once
    }
    __syncthreads();
}

// ============ k_all (R14): single persistent kernel, 512 blocks x 256 thr,
// 65,568 B static LDS -> exactly 2 blocks/CU. Phase bodies verbatim R6
// (which passed bit-exact); ONLY the barrier implementation changed.
__global__ void __launch_bounds__(256, 2) k_all(const float* __restrict__ x,
                                                const float* __restrict__ W1,
                                                const float* __restrict__ W2,
                                                float* __restrict__ W1Ts,
                                                uint64_t* __restrict__ mask,
                                                float* __restrict__ srm28,
                                                uint16_t* glst,          // aliases a1 (time-disjoint)
                                                int* __restrict__ gcnt,
                                                float* __restrict__ z1,
                                                float* a1,               // aliases glst
                                                uint64_t* __restrict__ smaskg,
                                                int* __restrict__ bar,
                                                float* __restrict__ out) {
    __shared__ __align__(16) char smem[65568];
    int bid = blockIdx.x;
    int tid = threadIdx.x;

    // ================= P1: prep (pack + W1 transpose + srm/zero) =================
    for (int vb = bid; vb < 2049; vb += GRID) {
        if (vb < 1024) {
            uint64_t (*tb)[64] = (uint64_t(*)[64])smem;     // 3 KB
            int b = vb >> 5, nblk = vb & 31;
            int wv = tid >> 6, lane = tid & 63;
            for (int g = 0; g < 4; ++g) {
                float v[4][6];
                #pragma unroll
                for (int i = 0; i < 4; ++i) {
                    int nr = wv + 4 * (4 * g + i);
                    const float* xp = x + ((size_t)b * NIN + nblk * 64 + nr) * T;
                    #pragma unroll
                    for (int c = 0; c < 6; ++c) {
                        int t = c * 64 + lane;
                        v[i][c] = (t < T) ? xp[t] : 0.f;
                    }
                }
                #pragma unroll
                for (int i = 0; i < 4; ++i) {
                    int nr = wv + 4 * (4 * g + i);
                    #pragma unroll
                    for (int c = 0; c < 6; ++c) {
                        uint64_t mk = __ballot(v[i][c] != 0.0f);
                        if (lane == 0) tb[c][nr] = mk;
                    }
                }
            }
            __syncthreads();
            static const uint64_t AM[6] = {
                0x00000000FFFFFFFFull, 0x0000FFFF0000FFFFull, 0x00FF00FF00FF00FFull,
                0x0F0F0F0F0F0F0F0Full, 0x3333333333333333ull, 0x5555555555555555ull };
            for (int c = wv; c < 6; c += 4) {
                uint64_t w = tb[c][lane];            // lane = n, bits = t
                #pragma unroll
                for (int i = 0; i < 6; ++i) {
                    int s = 32 >> i;
                    uint64_t A = AM[i];
                    uint64_t y = __shfl_xor((unsigned long long)w, s);
                    if ((lane & s) == 0) w = (w & A)  | ((y & A) << s);
                    else                 w = (w & ~A) | ((y & ~A) >> s);
                }
                int t = c * 64 + lane;               // lane = t, bits = n
                if (t < T) mask[((size_t)b * 32 + nblk) * 352 + t] = w;
            }
        } else if (vb < 2048) {
            float (*tile)[33] = (float(*)[33])smem;          // 4.2 KB
            int idx = vb - 1024;
            int n0 = (idx & 63) * 32, m0 = (idx >> 6) * 32;
            int tx = tid & 31, ty0 = tid >> 5;
            #pragma unroll
            for (int i = 0; i < 4; ++i) {
                int ty = ty0 + 8 * i;
                tile[ty][tx] = W1[(size_t)(m0 + ty) * NIN + n0 + tx];
            }
            __syncthreads();
            #pragma unroll
            for (int i = 0; i < 4; ++i) {
                int ty = ty0 + 8 * i;
                int n = n0 + ty, m = m0 + tx;
                W1Ts[(size_t)(m >> 3) * SLICE_STRIDE + n * SLICE_F + (m & 7)] = tile[tx][ty];
            }
        } else {
            int j = tid;
            if (j < 192) {
                float v = 0.f;
                int i = j - 28;
                if (i >= 0 && i < 100) { float t = (float)i; v = (t * 0.1f) * expf(1.f - t * 0.1f); }
                srm28[j] = v;
            }
            for (int i = j; i < NSLICE * SLICE_F; i += 256)
                W1Ts[(size_t)(i >> 3) * SLICE_STRIDE + 2048 * SLICE_F + (i & 7)] = 0.f;
        }
        __syncthreads();   // protect smem reuse across vb iterations (block-uniform)
    }
    gbar(bar, 0);

    // ================= P2: decode (per-wave; uniform 6-iter loop) =================
    {
        int w = tid >> 6, lane = tid & 63;
        uint16_t* lst = (uint16_t*)smem + w * 200;   // 400 B per wave
        int vw = bid * 4 + w;                        // 0..2047
        for (int k = 0; k < 6; ++k) {
            int row = vw + 2048 * k;
            bool act = (row < BT);
            int padded = 0;
            if (act) {
                int b = row / T, t = row - b * T;
                uint64_t wd = (lane < 32) ? mask[((size_t)b * 32 + lane) * 352 + t] : 0ull;
                int cnt = __popcll(wd);
                int pre = cnt;
                #pragma unroll
                for (int off = 1; off < 64; off <<= 1) {
                    int v = __shfl_up(pre, off);
                    if (lane >= off) pre += v;
                }
                int total = __shfl(pre, 63);
                int excl = pre - cnt;
                while (wd) {
                    int bit = __builtin_ctzll(wd);
                    wd &= wd - 1;
                    lst[excl++] = (uint16_t)((lane << 6) + bit);
                }
                padded = (total + 7) & ~7;
                if (lane < padded - total) lst[total + lane] = 2048;   // zero-row pad
            }
            __syncthreads();    // uniform across all 4 waves
            if (act) {
                uint16_t* op = glst + (size_t)row * 192;
                for (int i = lane; i < padded; i += 64) op[i] = lst[i];
                if (lane == 0) gcnt[row] = padded;
            }
            __syncthreads();
        }
    }
    gbar(bar, 1);

    // ================= P3: z1 gather (verbatim k_z1s; 512 blocks exact) ==========
    {
        float* w1s = (float*)smem;                  // 65,568 B
        int s = bid & 63;
        int bt0 = (bid >> 6) * (BT / 8);            // 1400 rows per block
        const float4* src = (const float4*)(W1Ts + (size_t)s * SLICE_STRIDE);
        for (int i = tid; i < SLICE_STRIDE / 4; i += 256)
            ((float4*)w1s)[i] = src[i];
        __syncthreads();

        int q  = tid & 1;
        int rl = tid >> 1;
        for (int rr = rl; rr < BT / 8; rr += 128) {
            int row = bt0 + rr;
            int padded = gcnt[row];
            const ushort4* lp = (const ushort4*)(glst + (size_t)row * 192);
            float4 acc = {0, 0, 0, 0};
            for (int k = 0; k < padded; k += 8) {
                ushort4 q0 = lp[k >> 2];
                ushort4 q1 = lp[(k >> 2) + 1];
                const float* base = w1s + q * 4;
                float4 x0 = *(const float4*)(base + q0.x * SLICE_F);
                float4 x1 = *(const float4*)(base + q0.y * SLICE_F);
                float4 x2 = *(const float4*)(base + q0.z * SLICE_F);
                float4 x3 = *(const float4*)(base + q0.w * SLICE_F);
                float4 x4 = *(const float4*)(base + q1.x * SLICE_F);
                float4 x5 = *(const float4*)(base + q1.y * SLICE_F);
                float4 x6 = *(const float4*)(base + q1.z * SLICE_F);
                float4 x7 = *(const float4*)(base + q1.w * SLICE_F);
                acc.x += x0.x; acc.y += x0.y; acc.z += x0.z; acc.w += x0.w;
                acc.x += x1.x; acc.y += x1.y; acc.z += x1.z; acc.w += x1.w;
                acc.x += x2.x; acc.y += x2.y; acc.z += x2.z; acc.w += x2.w;
                acc.x += x3.x; acc.y += x3.y; acc.z += x3.z; acc.w += x3.w;
                acc.x += x4.x; acc.y += x4.y; acc.z += x4.z; acc.w += x4.w;
                acc.x += x5.x; acc.y += x5.y; acc.z += x5.z; acc.w += x5.w;
                acc.x += x6.x; acc.y += x6.y; acc.z += x6.z; acc.w += x6.w;
                acc.x += x7.x; acc.y += x7.y; acc.z += x7.z; acc.w += x7.w;
            }
            *(float4*)(z1 + (size_t)row * NH + s * SLICE_F + q * 4) = acc;
        }
    }
    gbar(bar, 2);

    // ================= P4: fir1 (verbatim R4 Toeplitz; one wave per vblock) ======
    {
        float* tbf = (float*)smem;                  // 192 floats
        for (int i = tid; i < 192; i += 256) tbf[i] = srm28[i];
        __syncthreads();
        int w = tid >> 6, lane = tid & 63;
        int vw = bid * 4 + w;                        // 0..2047; 1408 active
        if (vw < 1408) {
            int b = vw & 31, half = (vw >> 5) & 1, tg = vw >> 6;  // tg 0..21
            int t0 = tg * 16;
            int m = half * 256 + lane * 4;
            const float* sp = z1 + (size_t)b * T * NH + m;

            float4 acc[16];
            #pragma unroll
            for (int r = 0; r < 16; ++r) acc[r] = make_float4(0.f, 0.f, 0.f, 0.f);

            int o_start = (99 - t0) >> 4;
            if (o_start < 0) o_start = 0;

            for (int o = o_start; o < 7; ++o) {      // NOT unrolled (R3 lesson)
                float cw[31];
                int cb = 112 - 16 * o;
                #pragma unroll
                for (int kk = 0; kk < 31; ++kk) cw[kk] = tbf[cb + kk];
                int dd0 = o * 16;
                #pragma unroll
                for (int j = 0; j < 16; ++j) {
                    int tau = t0 - 99 + dd0 + j;
                    float4 v = make_float4(0.f, 0.f, 0.f, 0.f);
                    if (tau >= 0 && tau < T) v = *(const float4*)(sp + (size_t)tau * NH);
                    #pragma unroll
                    for (int r = 0; r < 16; ++r) {
                        float c = cw[r - j + 15];
                        acc[r].x += c * v.x; acc[r].y += c * v.y;
                        acc[r].z += c * v.z; acc[r].w += c * v.w;
                    }
                }
            }
            {   // o == 7 tail
                float e1 = tbf[29], e2 = tbf[30];
                int tau = t0 + 13;
                if (tau < T) {
                    float4 v = *(const float4*)(sp + (size_t)tau * NH);
                    acc[14].x += e1 * v.x; acc[14].y += e1 * v.y;
                    acc[14].z += e1 * v.z; acc[14].w += e1 * v.w;
                    acc[15].x += e2 * v.x; acc[15].y += e2 * v.y;
                    acc[15].z += e2 * v.z; acc[15].w += e2 * v.w;
                }
                tau = t0 + 14;
                if (tau < T) {
                    float4 v = *(const float4*)(sp + (size_t)tau * NH);
                    acc[15].x += e1 * v.x; acc[15].y += e1 * v.y;
                    acc[15].z += e1 * v.z; acc[15].w += e1 * v.w;
                }
            }
            #pragma unroll
            for (int r = 0; r < 16; ++r) {
                int t = t0 + r;
                if (t < T) *(float4*)(a1 + ((size_t)b * T + t) * NH + m) = acc[r];
            }
        }
    }
    gbar(bar, 3);

    // ================= P5: scan1 (verbatim; wave 0 of even blocks = 256 waves) ===
    {
        if ((bid & 1) == 0 && tid < 64) {
            constexpr int CT = 16;
            constexpr int NC = (T + CT - 1) / CT;   // 22
            int tg = (bid >> 1) * 64 + tid;
            int b = tg >> 9, m = tg & 511;
            int w8 = m >> 6;
            const float* up = a1 + (size_t)b * T * NH + m;
            float A = 0.f, Bs = 0.f;
            float c0[CT], c1[CT], c2[CT];
            #pragma unroll
            for (int j = 0; j < CT; ++j) c0[j] = up[(size_t)j * NH];
            #pragma unroll
            for (int j = 0; j < CT; ++j) {
                int t = CT + j;
                c1[j] = (t < T) ? up[(size_t)t * NH] : 0.f;
            }
            for (int c = 0; c < NC; ++c) {
                int t0 = c * CT;
                int nsteps = (T - t0 < CT) ? (T - t0) : CT;
                if (c + 2 < NC) {
                    #pragma unroll
                    for (int j = 0; j < CT; ++j) {
                        int t = t0 + 2 * CT + j;
                        c2[j] = (t < T) ? up[(size_t)t * NH] : 0.f;
                    }
                }
                #pragma unroll
                for (int j = 0; j < CT; ++j) {
                    if (j < nsteps) {                 // uniform -> safe ballot
                        float mem = c0[j] - CREF * Bs;
                        float sp = (mem >= THETA) ? 1.0f : 0.0f;
                        A = sp + BETA * A;
                        Bs = BETA * (Bs + A);
                        uint64_t mk = __ballot(sp != 0.0f);
                        if (tid == 0) smaskg[((size_t)b * T + t0 + j) * 8 + w8] = mk;
                    }
                }
                #pragma unroll
                for (int j = 0; j < CT; ++j) { c0[j] = c1[j]; c1[j] = c2[j]; }
            }
        }
    }
    gbar(bar, 4);

    // ================= P6: tail (verbatim; 32 spread blocks) =====================
    if ((bid & 15) == 0) {
        int b = bid >> 4;                           // 0..31
        float*    w2s_ab = (float*)smem;                      // 20,480 B
        uint64_t* smk    = (uint64_t*)(smem + 20480);         // 22,400 B
        float*    tbf    = (float*)(smem + 42880);            //    768 B
        float*    zb     = (float*)(smem + 43648);            // 15,464 B (stride 11)
        for (int i = tid; i < NO * NH; i += 256) w2s_ab[i] = W2[i];
        const uint64_t* mp = smaskg + (size_t)b * T * 8;
        for (int i = tid; i < T * 8; i += 256) smk[i] = mp[i];
        if (tid < 192) tbf[tid] = srm28[tid];
        __syncthreads();
        // ---- z2 gather: ascending w8 / ascending bit = ascending m (bit-exact)
        for (int i = tid; i < T * NO; i += 256) {
            int t = i / NO, o = i - t * NO;
            const float* wrow = w2s_ab + o * NH;
            float acc = 0.f;
            #pragma unroll
            for (int w8 = 0; w8 < 8; ++w8) {
                uint64_t mk = smk[t * 8 + w8];
                int base = w8 * 64;
                while (mk) {
                    int bit = __builtin_ctzll(mk);
                    mk &= mk - 1;
                    acc += wrow[base + bit];
                }
            }
            zb[t * 11 + o] = acc;
        }
        __syncthreads();
        // ---- fir2: zb -> ab (ab aliases w2s, dead after gather)
        float* ab = w2s_ab;
        if (tid < 220) {
            int tt = tid / 10, o = tid - tt * 10;
            int t0 = tt * 16;
            float acc[16];
            #pragma unroll
            for (int r = 0; r < 16; ++r) acc[r] = 0.f;
            float c[16];
            #pragma unroll
            for (int r = 0; r < 16; ++r) c[r] = tbf[r + 127];
            for (int oo = 0; oo < 8; ++oo) {
                #pragma unroll
                for (int j = 0; j < 16; ++j) {
                    int dd = oo * 16 + j;
                    int tau = t0 - 99 + dd;
                    float v = (tau >= 0 && tau < T) ? zb[tau * 11 + o] : 0.f;
                    #pragma unroll
                    for (int r = 0; r < 16; ++r) acc[r] += c[r] * v;
                    #pragma unroll
                    for (int r = 15; r > 0; --r) c[r] = c[r - 1];
                    int ci = 126 - dd;
                    c[0] = tbf[ci < 0 ? 0 : ci];
                }
            }
            #pragma unroll
            for (int r = 0; r < 16; ++r) {
                int t = t0 + r;
                if (t < T) ab[t * 10 + o] = acc[r];
            }
        }
        __syncthreads();
        // ---- final refractory scan -> out [B][NO][T]
        if (tid < NO) {
            int o = tid;
            float A2 = 0.f, B2 = 0.f;
            float* op = out + ((size_t)b * NO + o) * T;
            for (int t = 0; t < T; ++t) {
                float mem = ab[t * 10 + o] - CREF * B2;
                float sp = (mem >= THETA) ? 1.0f : 0.0f;
                A2 = sp + BETA * A2;
                B2 = BETA * (B2 + A2);
                op[t] = sp;
            }
        }
    }
}

extern "C" void kernel_launch(void* const* d_in, const int* in_sizes, int n_in,
                              void* d_out, int out_size, void* d_ws, size_t ws_size,
                              hipStream_t stream) {
    const float* x  = (const float*)d_in[0];
    const float* W1 = (const float*)d_in[1];
    const float* W2 = (const float*)d_in[2];
    char* ws = (char*)d_ws;
    float*    W1Ts   = (float*)(ws + OFF_W1TS);
    uint64_t* mask   = (uint64_t*)(ws + OFF_MASK);
    float*    srm    = (float*)(ws + OFF_SRM);
    float*    z1     = (float*)(ws + OFF_Z1);
    float*    a1     = (float*)(ws + OFF_A1);
    uint16_t* glst   = (uint16_t*)(ws + OFF_LST);   // overlays a1 (time-disjoint)
    int*      gcnt   = (int*)(ws + OFF_CNT);
    uint64_t* smaskg = (uint64_t*)(ws + OFF_SMK);
    int*      bar    = (int*)(ws + OFF_BAR);
    float*    out    = (float*)d_out;

    // zero the 5 barrier counters (graph-capture legal memset node)
    (void)hipMemsetAsync(bar, 0, 64, stream);
    hipLaunchKernelGGL(k_all, dim3(GRID), dim3(256), 0, stream,
                       x, W1, W2, W1Ts, mask, srm, glst, gcnt, z1, a1,
                       smaskg, bar, out);
}